// Round 8
// baseline (1060.076 us; speedup 1.0000x reference)
//
#include <hip/hip_runtime.h>

constexpr int B  = 16;
constexpr int S  = 128;
constexpr int NC = 100;
constexpr int DK = 128;
constexpr int T  = S - 1;

typedef __attribute__((ext_vector_type(8))) short bf16x8;
typedef __attribute__((ext_vector_type(8))) unsigned short u16x8;
typedef __attribute__((ext_vector_type(4))) float f32x4;

__device__ __forceinline__ float sigm(float x) {
  return __builtin_amdgcn_rcpf(1.0f + __expf(-x));
}
__device__ __forceinline__ float tanh_fast(float x) {
  return 2.0f * __builtin_amdgcn_rcpf(1.0f + __expf(-2.0f * x)) - 1.0f;
}
__device__ __forceinline__ unsigned short f2bf(float x) {   // RNE f32 -> bf16
  unsigned u = __float_as_uint(x);
  u += 0x7fff + ((u >> 16) & 1);
  return (unsigned short)(u >> 16);
}
// round-half-up bf16 pack: hi16(a+0.5ulp) low, hi16(b+0.5ulp) high
__device__ __forceinline__ unsigned pkrta(float a, float b) {
  unsigned ua = __float_as_uint(a) + 0x8000u;
  unsigned ub = __float_as_uint(b) + 0x8000u;
  return __builtin_amdgcn_perm(ub, ua, 0x07060302u);
}
__device__ __forceinline__ float bfhi(unsigned short v) {
  return __uint_as_float(((unsigned)v) << 16);
}
// padded index: +4 words after each 32-float chunk
__device__ __forceinline__ int pk(int k) { return k + ((k >> 5) << 2); }

// ---------------------------------------------------------------------------
// Kernel 1: AL[b,s,:] = [e_emb, at_emb, corr] @ W1 + b1   (8 s per block)
// ---------------------------------------------------------------------------
__global__ void k_all_learning(const int* __restrict__ qs, const int* __restrict__ ats,
                               const float* __restrict__ corr,
                               const float* __restrict__ e_w, const float* __restrict__ at_w,
                               const float* __restrict__ W1, const float* __restrict__ b1,
                               float* __restrict__ AL) {
  int b = blockIdx.x >> 4, c = blockIdx.x & 15;
  int s0 = c * 8;
  int j = threadIdx.x;
  __shared__ float ve[8][DK], va[8][DK];
  __shared__ float cr[8];
#pragma unroll
  for (int i = 0; i < 8; ++i) {
    int bs = b * S + s0 + i;
    ve[i][j] = e_w[qs[bs] * DK + j];
    va[i][j] = at_w[ats[bs] * DK + j];
    if (j == 0) cr[i] = corr[bs];
  }
  __syncthreads();
  float acc[8];
  float cs = 0.0f;
#pragma unroll 4
  for (int k = 0; k < DK; ++k) cs += W1[(2 * DK + k) * DK + j];
  float bj = b1[j];
#pragma unroll
  for (int i = 0; i < 8; ++i) acc[i] = bj + cr[i] * cs;
#pragma unroll 2
  for (int k = 0; k < DK; ++k) {
    float we = W1[k * DK + j];
    float wa = W1[(DK + k) * DK + j];
#pragma unroll
    for (int i = 0; i < 8; ++i) {
      acc[i] = fmaf(ve[i][k], we, acc[i]);
      acc[i] = fmaf(va[i][k], wa, acc[i]);
    }
  }
#pragma unroll
  for (int i = 0; i < 8; ++i) AL[(b * S + s0 + i) * DK + j] = acc[i];
}

// ---------------------------------------------------------------------------
// Kernel 2: per (b,t): K2/K3 (x4@W2/W3 minus h_tilde part), C4, C5.
// ---------------------------------------------------------------------------
__global__ void k_consts(const int* __restrict__ qs, const int* __restrict__ its,
                         const float* __restrict__ it_w, const float* __restrict__ e_w,
                         const float* __restrict__ AL,
                         const float* __restrict__ W2, const float* __restrict__ b2,
                         const float* __restrict__ W3, const float* __restrict__ b3,
                         const float* __restrict__ W4, const float* __restrict__ b4,
                         const float* __restrict__ W5, const float* __restrict__ b5,
                         float* __restrict__ K2, float* __restrict__ K3,
                         float* __restrict__ C4, float* __restrict__ C5) {
  int b = blockIdx.x >> 4, c = blockIdx.x & 15;
  int t0 = c * 8;
  int nt = (t0 + 8 <= T) ? 8 : (T - t0);
  int j = threadIdx.x;
  __shared__ float lp[8][DK], itv[8][DK], lc[8][DK], en[8][DK];
  for (int i = 0; i < nt; ++i) {
    int bs = b * S + t0 + i;
    lp[i][j]  = (t0 + i == 0) ? 0.0f : AL[(bs - 1) * DK + j];
    lc[i][j]  = AL[bs * DK + j];
    itv[i][j] = it_w[its[bs] * DK + j];
    en[i][j]  = e_w[qs[bs + 1] * DK + j];
  }
  __syncthreads();
  float a2[8], a3[8], a4[8], a5[8];
  float v2 = b2[j], v3 = b3[j], v4 = b4[j], v5 = b5[j];
#pragma unroll
  for (int i = 0; i < 8; ++i) { a2[i] = v2; a3[i] = v3; a4[i] = v4; a5[i] = v5; }
#pragma unroll 2
  for (int k = 0; k < DK; ++k) {
    float w2a = W2[k * DK + j], w2b = W2[(DK + k) * DK + j], w2c = W2[(2 * DK + k) * DK + j];
    float w3a = W3[k * DK + j], w3b = W3[(DK + k) * DK + j], w3c = W3[(2 * DK + k) * DK + j];
    float w4c = W4[(2 * DK + k) * DK + j];
    float w5a = W5[k * DK + j];
#pragma unroll
    for (int i = 0; i < 8; ++i) {
      float vlp = lp[i][k], vit = itv[i][k], vlc = lc[i][k], ven = en[i][k];
      a2[i] = fmaf(vlp, w2a, a2[i]); a2[i] = fmaf(vit, w2b, a2[i]); a2[i] = fmaf(vlc, w2c, a2[i]);
      a3[i] = fmaf(vlp, w3a, a3[i]); a3[i] = fmaf(vit, w3b, a3[i]); a3[i] = fmaf(vlc, w3c, a3[i]);
      a4[i] = fmaf(vit, w4c, a4[i]);
      a5[i] = fmaf(ven, w5a, a5[i]);
    }
  }
  for (int i = 0; i < nt; ++i) {
    int o = (b * T + t0 + i) * DK + j;
    K2[o] = a2[i]; K3[o] = a3[i]; C4[o] = a4[i]; C5[o] = a5[i];
  }
}

// ---------------------------------------------------------------------------
// Kernel 3: scan. 1 block/batch, 1024 threads = 16 waves (wj=w&3, wn=w>>2).
// Per wave: 2 j-tiles x 2 n-tiles. 4 waves/SIMD for TLP (hide stalls).
// Two barriers per step:
//   [ M || A1 || C(prev) ]  b1  [ prefetch; A2 (wave-local); B2 ]  b3
// ---------------------------------------------------------------------------
__global__ __launch_bounds__(1024)
void k_scan(const int* __restrict__ qs,
            const float* __restrict__ qmat,
            const float* __restrict__ h0,
            const float* __restrict__ K2, const float* __restrict__ K3,
            const float* __restrict__ C4, const float* __restrict__ C5,
            const float* __restrict__ W2, const float* __restrict__ W3,
            const float* __restrict__ W4, const float* __restrict__ W5,
            float* __restrict__ out) {
  const int b   = blockIdx.x;
  const int tid = threadIdx.x;
  const int w   = tid >> 6;        // 0..15
  const int l   = tid & 63;
  const int l15 = l & 15;
  const int g   = l >> 4;          // 0..3  (MFMA fragment row group)
  const int wj  = w & 3;           // j-block of 32 cols
  const int wn  = w >> 2;          // 0..3: n-tiles {2wn, 2wn+1}
  const int gc8 = 8 * w + (l & 7); // A1/C output column (8 cols per wave)
  const int g8  = l >> 3;          // 0..7  (A1/C k-group, 16 k each)
  const int ac  = 32 * wj + (l & 31);  // A2 column
  const int akb = (l >> 5) * 64;       // A2 k-half base

  __shared__ alignas(16) unsigned short hBH[14336];        // h bf16, frag order (7 n-tiles)
  __shared__ alignas(16) unsigned short W4X[16 * 132 * 8]; // W4b^T bf16: [kc][col][8]
  __shared__ alignas(16) unsigned short W5X[16 * 132 * 8]; // W5b^T bf16: [kc][col][8]
  __shared__ alignas(16) float sLG[144];
  __shared__ alignas(16) float sHT[2][144];                // h_tilde double buffer
  __shared__ alignas(16) float sQ[2][DK];
  __shared__ float sY[16];

  const float* W2d = W2 + 3 * DK * DK;
  const float* W3d = W3 + 3 * DK * DK;
  const float* W4a = W4;
  const float* W4b = W4 + DK * DK;
  const float* W5b = W5 + DK * DK;

  // ---- per-lane f32 weights for A1 (16 k x 1 col each)
  float w2r[16], w3r[16];
#pragma unroll
  for (int kk = 0; kk < 16; ++kk) {
    w2r[kk] = W2d[(16 * g8 + kk) * DK + gc8];
    w3r[kk] = W3d[(16 * g8 + kk) * DK + gc8];
  }

  // ---- W4b / W5b -> LDS in [kc][col][8] layout (conflict-free b128 reads)
  for (int i = tid; i < DK * DK; i += 1024) {
    int k = i >> 7, j = i & 127;
    int o = ((k >> 3) * 132 + j) * 8 + (k & 7);
    W4X[o] = f2bf(W4b[i]);
    W5X[o] = f2bf(W5b[i]);
  }

  // ---- A-fragments: A = W4a^T (bf16), 2 j-tiles per wave
  bf16x8 afr[2][4];
#pragma unroll
  for (int jt = 0; jt < 2; ++jt) {
    int j = 32 * wj + 16 * jt + l15;
#pragma unroll
    for (int ks = 0; ks < 4; ++ks) {
      bf16x8 v;
#pragma unroll
      for (int e = 0; e < 8; ++e) v[e] = (short)f2bf(W4a[(ks * 32 + g * 8 + e) * DK + j]);
      afr[jt][ks] = v;
    }
  }

  if (tid < DK) sQ[0][tid] = (tid < NC) ? qmat[qs[b * S] * NC + tid] : 0.0f;
  if (tid == 0) out[b * S] = 0.0f;
  if (tid < 144) { sHT[0][tid] = 0.0f; sHT[1][tid] = 0.0f; }

  // ---- init h registers (C layout) + fragment-order bf16 LDS
  float hold[2][2][4];
#pragma unroll
  for (int jt = 0; jt < 2; ++jt) {
    int j4 = 32 * wj + 16 * jt + 4 * g;
    int ks = j4 >> 5, lg = (j4 >> 3) & 3;
#pragma unroll
    for (int nt = 0; nt < 2; ++nt) {
      int ntg = 2 * wn + nt;
      if (ntg == 7) {
#pragma unroll
        for (int r = 0; r < 4; ++r) hold[jt][nt][r] = 0.0f;
        continue;
      }
      int n = 16 * ntg + l15;
      float x0 = (n < NC) ? h0[n * DK + j4 + 0] : 0.0f;
      float x1 = (n < NC) ? h0[n * DK + j4 + 1] : 0.0f;
      float x2 = (n < NC) ? h0[n * DK + j4 + 2] : 0.0f;
      float x3 = (n < NC) ? h0[n * DK + j4 + 3] : 0.0f;
      hold[jt][nt][0] = x0; hold[jt][nt][1] = x1;
      hold[jt][nt][2] = x2; hold[jt][nt][3] = x3;
      uint2 vh;
      vh.x = pkrta(x0, x1); vh.y = pkrta(x2, x3);
      int idx = ((ntg * 4 + ks) * 64 + (lg << 4) + l15) * 8 + ((j4 & 4) ? 4 : 0);
      *(uint2*)&hBH[idx] = vh;
    }
  }
  __syncthreads();

  // ---- h_tilde0 -> sHT[0]
  {
#pragma unroll
    for (int jt = 0; jt < 2; ++jt) {
      int j4 = 32 * wj + 16 * jt + 4 * g;
      float htp[4] = {0.f, 0.f, 0.f, 0.f};
#pragma unroll
      for (int nt = 0; nt < 2; ++nt) {
        int ntg = 2 * wn + nt;
        if (ntg == 7) continue;
        int n = 16 * ntg + l15;
        float qe = sQ[0][n];
#pragma unroll
        for (int r = 0; r < 4; ++r) htp[r] = fmaf(qe, hold[jt][nt][r], htp[r]);
      }
#pragma unroll
      for (int r = 0; r < 4; ++r) {
        float v = htp[r];
        v += __shfl_xor(v, 1, 64); v += __shfl_xor(v, 2, 64);
        v += __shfl_xor(v, 4, 64); v += __shfl_xor(v, 8, 64);
        if (l15 == 0) atomicAdd(&sHT[0][pk(j4 + r)], v);
      }
    }
  }
  __syncthreads();

  // ---- prefetch registers
  float k2v = K2[(b * T) * DK + gc8], k3v = K3[(b * T) * DK + gc8];
  float c4_pf = C4[(b * T) * DK + ac];
  float c5_pf = C5[(b * T) * DK + gc8];
  float c5_use = 0.0f;
  float qnew = (tid < NC) ? qmat[qs[b * S + 1] * NC + tid] : 0.0f;

  // A1/C read base into sHT: k-range [16*g8, 16*g8+16) is pk-contiguous
  const int hb = 16 * g8 + 4 * (g8 >> 1);

  for (int t = 0; t < T; ++t) {
    const int cur = t & 1, nxt = cur ^ 1;

    // ================= pre-b1: M || A1 || C(prev) =================

    // ---- Phase M: dot = W4a^T x h^T (single bf16)
    f32x4 acc[2][2];
#pragma unroll
    for (int jt = 0; jt < 2; ++jt)
#pragma unroll
      for (int nt = 0; nt < 2; ++nt) acc[jt][nt] = (f32x4){0.f, 0.f, 0.f, 0.f};
#pragma unroll
    for (int nt = 0; nt < 2; ++nt) {
      int ntg = 2 * wn + nt;
      if (ntg == 7) continue;
      bf16x8 bh[4];
#pragma unroll
      for (int ks = 0; ks < 4; ++ks)
        bh[ks] = *(const bf16x8*)&hBH[(ntg * 4 + ks) * 512 + l * 8];
#pragma unroll
      for (int ks = 0; ks < 4; ++ks)
#pragma unroll
        for (int jt = 0; jt < 2; ++jt)
          acc[jt][nt] = __builtin_amdgcn_mfma_f32_16x16x32_bf16(afr[jt][ks], bh[ks], acc[jt][nt], 0, 0, 0);
    }

    // ---- Phase C (for step t-1): y = mean(sigmoid(C5 + h_tilde@W5b))
    if (t > 0) {
      float pa = 0.f, pb = 0.f;
      float4 h0v = *(const float4*)&sHT[cur][hb];
      float4 h1v = *(const float4*)&sHT[cur][hb + 4];
      float4 h2v = *(const float4*)&sHT[cur][hb + 8];
      float4 h3v = *(const float4*)&sHT[cur][hb + 12];
#pragma unroll
      for (int m = 0; m < 2; ++m) {
        u16x8 wv = *(const u16x8*)&W5X[((2 * g8 + m) * 132 + gc8) * 8];
        float4 ha = (m == 0) ? h0v : h2v;
        float4 hbv = (m == 0) ? h1v : h3v;
        pa = fmaf(ha.x, bfhi(wv[0]), pa);
        pb = fmaf(ha.y, bfhi(wv[1]), pb);
        pa = fmaf(ha.z, bfhi(wv[2]), pa);
        pb = fmaf(ha.w, bfhi(wv[3]), pb);
        pa = fmaf(hbv.x, bfhi(wv[4]), pa);
        pb = fmaf(hbv.y, bfhi(wv[5]), pb);
        pa = fmaf(hbv.z, bfhi(wv[6]), pa);
        pb = fmaf(hbv.w, bfhi(wv[7]), pb);
      }
      float p = pa + pb;
      p += __shfl_xor(p, 8, 64); p += __shfl_xor(p, 16, 64); p += __shfl_xor(p, 32, 64);
      float u = sigm(c5_use + p);
      u += __shfl_xor(u, 1, 64); u += __shfl_xor(u, 2, 64); u += __shfl_xor(u, 4, 64);
      if (l == 0) sY[w] = u;
    }

    // ---- Phase A1: LG from h_tilde (weights in VGPRs, 16 k x 1 col per lane)
    {
      float p2a = 0.f, p2b = 0.f, p3a = 0.f, p3b = 0.f;
#pragma unroll
      for (int m = 0; m < 4; ++m) {
        float4 hv = *(const float4*)&sHT[cur][hb + 4 * m];
        p2a = fmaf(hv.x, w2r[4 * m + 0], p2a); p3a = fmaf(hv.x, w3r[4 * m + 0], p3a);
        p2b = fmaf(hv.y, w2r[4 * m + 1], p2b); p3b = fmaf(hv.y, w3r[4 * m + 1], p3b);
        p2a = fmaf(hv.z, w2r[4 * m + 2], p2a); p3a = fmaf(hv.z, w3r[4 * m + 2], p3a);
        p2b = fmaf(hv.w, w2r[4 * m + 3], p2b); p3b = fmaf(hv.w, w3r[4 * m + 3], p3b);
      }
      float p2 = p2a + p2b, p3 = p3a + p3b;
      p2 += __shfl_xor(p2, 8, 64); p2 += __shfl_xor(p2, 16, 64); p2 += __shfl_xor(p2, 32, 64);
      p3 += __shfl_xor(p3, 8, 64); p3 += __shfl_xor(p3, 16, 64); p3 += __shfl_xor(p3, 32, 64);
      if (l < 8) {
        float x2 = k2v + p2, x3 = k3v + p3;
        sLG[pk(gc8)] = sigm(x3) * (tanh_fast(x2) + 1.0f) * 0.5f;
      }
      if (tid < DK) {
        sQ[nxt][tid] = qnew;
        sHT[nxt][pk(tid)] = 0.0f;     // zero the buffer B2 will accumulate into
      }
    }
    __syncthreads();                                  // b1

    // ================= post-b1: y-write; prefetch; A2; B2 =================

    if (t > 0 && tid == 0) {
      float s = 0.f;
#pragma unroll
      for (int i = 0; i < 16; ++i) s += sY[i];
      out[b * S + t] = s * (1.0f / DK);
    }

    // shift + issue prefetches for next iteration (overlap with A2+B2)
    float c4_use = c4_pf;
    c5_use = c5_pf;
    {
      int tn  = (t + 1 < T) ? (t + 1) : (T - 1);
      int btn = (b * T + tn) * DK;
      k2v = K2[btn + gc8]; k3v = K3[btn + gc8];
      c4_pf = C4[btn + ac]; c5_pf = C5[btn + gc8];
      int rq = (t + 2 < S) ? (t + 2) : (S - 1);
      qnew = (tid < NC) ? qmat[qs[b * S + rq] * NC + tid] : 0.0f;
    }

    // ---- Phase A2 (wave-local): V[ac] = C4 + LG @ W4b; distribute via shfl
    float vv[2][4];
    {
      float pa = 0.f, pb = 0.f;
#pragma unroll
      for (int mm = 0; mm < 8; ++mm) {
        int kc = (akb >> 3) + mm;
        u16x8 wv = *(const u16x8*)&W4X[(kc * 132 + ac) * 8];
        float4 a0 = *(const float4*)&sLG[pk(akb + 8 * mm)];
        float4 a1 = *(const float4*)&sLG[pk(akb + 8 * mm + 4)];
        pa = fmaf(a0.x, bfhi(wv[0]), pa);
        pb = fmaf(a0.y, bfhi(wv[1]), pb);
        pa = fmaf(a0.z, bfhi(wv[2]), pa);
        pb = fmaf(a0.w, bfhi(wv[3]), pb);
        pa = fmaf(a1.x, bfhi(wv[4]), pa);
        pb = fmaf(a1.y, bfhi(wv[5]), pb);
        pa = fmaf(a1.z, bfhi(wv[6]), pa);
        pb = fmaf(a1.w, bfhi(wv[7]), pb);
      }
      float V = pa + pb;
      V += __shfl_xor(V, 32, 64);
      V += c4_use;
#pragma unroll
      for (int jt = 0; jt < 2; ++jt)
#pragma unroll
        for (int r = 0; r < 4; ++r)
          vv[jt][r] = __shfl(V, 16 * jt + 4 * g + r, 64);
    }

    // ---- Phase B2: gamma_f, h update, writeback, h_tilde partials
    {
#pragma unroll
      for (int jt = 0; jt < 2; ++jt) {
        int j4 = 32 * wj + 16 * jt + 4 * g;
        float4 a = *(const float4*)&sLG[pk(j4)];
        float lgv[4] = {a.x, a.y, a.z, a.w};
        float htpr[4] = {0.f, 0.f, 0.f, 0.f};
        int ks = j4 >> 5, lg = (j4 >> 3) & 3;
#pragma unroll
        for (int nt = 0; nt < 2; ++nt) {
          int ntg = 2 * wn + nt;
          if (ntg == 7) continue;
          int n = 16 * ntg + l15;
          float qe = sQ[cur][n], qn = sQ[nxt][n];
          float hn[4];
#pragma unroll
          for (int r = 0; r < 4; ++r) {
            float gf = sigm(acc[jt][nt][r] + vv[jt][r]);
            hn[r] = fmaf(gf, hold[jt][nt][r], qe * lgv[r]);
            hold[jt][nt][r] = hn[r];
            htpr[r] = fmaf(qn, hn[r], htpr[r]);
          }
          uint2 vh;
          vh.x = pkrta(hn[0], hn[1]); vh.y = pkrta(hn[2], hn[3]);
          int idx = ((ntg * 4 + ks) * 64 + (lg << 4) + l15) * 8 + ((j4 & 4) ? 4 : 0);
          *(uint2*)&hBH[idx] = vh;
        }
#pragma unroll
        for (int r = 0; r < 4; ++r) {
          float v = htpr[r];
          v += __shfl_xor(v, 1, 64); v += __shfl_xor(v, 2, 64);
          v += __shfl_xor(v, 4, 64); v += __shfl_xor(v, 8, 64);
          if (l15 == 0) atomicAdd(&sHT[nxt][pk(j4 + r)], v);
        }
      }
    }
    __syncthreads();                                  // b3
  }

  // ---- final C for step T-1 + y write
  {
    const int fin = T & 1;
    float pa = 0.f, pb = 0.f;
#pragma unroll
    for (int m = 0; m < 2; ++m) {
      u16x8 wv = *(const u16x8*)&W5X[((2 * g8 + m) * 132 + gc8) * 8];
      float4 ha = *(const float4*)&sHT[fin][hb + 8 * m];
      float4 hbv = *(const float4*)&sHT[fin][hb + 8 * m + 4];
      pa = fmaf(ha.x, bfhi(wv[0]), pa);
      pb = fmaf(ha.y, bfhi(wv[1]), pb);
      pa = fmaf(ha.z, bfhi(wv[2]), pa);
      pb = fmaf(ha.w, bfhi(wv[3]), pb);
      pa = fmaf(hbv.x, bfhi(wv[4]), pa);
      pb = fmaf(hbv.y, bfhi(wv[5]), pb);
      pa = fmaf(hbv.z, bfhi(wv[6]), pa);
      pb = fmaf(hbv.w, bfhi(wv[7]), pb);
    }
    float p = pa + pb;
    p += __shfl_xor(p, 8, 64); p += __shfl_xor(p, 16, 64); p += __shfl_xor(p, 32, 64);
    float u = sigm(c5_use + p);
    u += __shfl_xor(u, 1, 64); u += __shfl_xor(u, 2, 64); u += __shfl_xor(u, 4, 64);
    if (l == 0) sY[w] = u;
  }
  __syncthreads();
  if (tid == 0) {
    float s = 0.f;
#pragma unroll
    for (int i = 0; i < 16; ++i) s += sY[i];
    out[b * S + T] = s * (1.0f / DK);
  }
}

extern "C" void kernel_launch(void* const* d_in, const int* in_sizes, int n_in,
                              void* d_out, int out_size, void* d_ws, size_t ws_size,
                              hipStream_t stream) {
  const int*   qs   = (const int*)d_in[0];
  const int*   ats  = (const int*)d_in[1];
  const int*   its  = (const int*)d_in[2];
  const float* corr = (const float*)d_in[3];
  const float* qmat = (const float*)d_in[4];
  const float* h0   = (const float*)d_in[5];
  const float* e_w  = (const float*)d_in[6];
  const float* at_w = (const float*)d_in[7];
  const float* it_w = (const float*)d_in[8];
  const float* W1 = (const float*)d_in[9];  const float* b1 = (const float*)d_in[10];
  const float* W2 = (const float*)d_in[11]; const float* b2 = (const float*)d_in[12];
  const float* W3 = (const float*)d_in[13]; const float* b3 = (const float*)d_in[14];
  const float* W4 = (const float*)d_in[15]; const float* b4 = (const float*)d_in[16];
  const float* W5 = (const float*)d_in[17]; const float* b5 = (const float*)d_in[18];
  float* out = (float*)d_out;

  float* AL = (float*)d_ws;              // B*S*DK
  float* K2 = AL + B * S * DK;           // B*T*DK
  float* K3 = K2 + B * T * DK;
  float* C4 = K3 + B * T * DK;
  float* C5 = C4 + B * T * DK;

  k_all_learning<<<dim3(B * 16), dim3(DK), 0, stream>>>(qs, ats, corr, e_w, at_w, W1, b1, AL);
  k_consts<<<dim3(B * 16), dim3(DK), 0, stream>>>(qs, its, it_w, e_w, AL,
                                                  W2, b2, W3, b3, W4, b4, W5, b5,
                                                  K2, K3, C4, C5);
  k_scan<<<dim3(B), dim3(1024), 0, stream>>>(qs, qmat, h0, K2, K3, C4, C5,
                                             W2, W3, W4, W5, out);
}

// Round 9
// 628.913 us; speedup vs baseline: 1.6856x; 1.6856x over previous
//
#include <hip/hip_runtime.h>

constexpr int B  = 16;
constexpr int S  = 128;
constexpr int NC = 100;
constexpr int DK = 128;
constexpr int T  = S - 1;

typedef __attribute__((ext_vector_type(8))) short bf16x8;
typedef __attribute__((ext_vector_type(8))) unsigned short u16x8;
typedef __attribute__((ext_vector_type(4))) float f32x4;

__device__ __forceinline__ float sigm(float x) {
  return __builtin_amdgcn_rcpf(1.0f + __expf(-x));
}
__device__ __forceinline__ float tanh_fast(float x) {
  return 2.0f * __builtin_amdgcn_rcpf(1.0f + __expf(-2.0f * x)) - 1.0f;
}
__device__ __forceinline__ unsigned short f2bf(float x) {   // RNE f32 -> bf16
  unsigned u = __float_as_uint(x);
  u += 0x7fff + ((u >> 16) & 1);
  return (unsigned short)(u >> 16);
}
// round-half-up bf16 pack: hi16(a+0.5ulp) low, hi16(b+0.5ulp) high
__device__ __forceinline__ unsigned pkrta(float a, float b) {
  unsigned ua = __float_as_uint(a) + 0x8000u;
  unsigned ub = __float_as_uint(b) + 0x8000u;
  return __builtin_amdgcn_perm(ub, ua, 0x07060302u);
}
__device__ __forceinline__ float bfhi(unsigned short v) {
  return __uint_as_float(((unsigned)v) << 16);
}
// padded index: +4 words after each 32-float chunk
__device__ __forceinline__ int pk(int k) { return k + ((k >> 5) << 2); }

// ---------------------------------------------------------------------------
// Kernel 1: AL[b,s,:] = [e_emb, at_emb, corr] @ W1 + b1   (8 s per block)
// ---------------------------------------------------------------------------
__global__ void k_all_learning(const int* __restrict__ qs, const int* __restrict__ ats,
                               const float* __restrict__ corr,
                               const float* __restrict__ e_w, const float* __restrict__ at_w,
                               const float* __restrict__ W1, const float* __restrict__ b1,
                               float* __restrict__ AL) {
  int b = blockIdx.x >> 4, c = blockIdx.x & 15;
  int s0 = c * 8;
  int j = threadIdx.x;
  __shared__ float ve[8][DK], va[8][DK];
  __shared__ float cr[8];
#pragma unroll
  for (int i = 0; i < 8; ++i) {
    int bs = b * S + s0 + i;
    ve[i][j] = e_w[qs[bs] * DK + j];
    va[i][j] = at_w[ats[bs] * DK + j];
    if (j == 0) cr[i] = corr[bs];
  }
  __syncthreads();
  float acc[8];
  float cs = 0.0f;
#pragma unroll 4
  for (int k = 0; k < DK; ++k) cs += W1[(2 * DK + k) * DK + j];
  float bj = b1[j];
#pragma unroll
  for (int i = 0; i < 8; ++i) acc[i] = bj + cr[i] * cs;
#pragma unroll 2
  for (int k = 0; k < DK; ++k) {
    float we = W1[k * DK + j];
    float wa = W1[(DK + k) * DK + j];
#pragma unroll
    for (int i = 0; i < 8; ++i) {
      acc[i] = fmaf(ve[i][k], we, acc[i]);
      acc[i] = fmaf(va[i][k], wa, acc[i]);
    }
  }
#pragma unroll
  for (int i = 0; i < 8; ++i) AL[(b * S + s0 + i) * DK + j] = acc[i];
}

// ---------------------------------------------------------------------------
// Kernel 2: per (b,t): K2/K3 (x4@W2/W3 minus h_tilde part), C4, C5.
// ---------------------------------------------------------------------------
__global__ void k_consts(const int* __restrict__ qs, const int* __restrict__ its,
                         const float* __restrict__ it_w, const float* __restrict__ e_w,
                         const float* __restrict__ AL,
                         const float* __restrict__ W2, const float* __restrict__ b2,
                         const float* __restrict__ W3, const float* __restrict__ b3,
                         const float* __restrict__ W4, const float* __restrict__ b4,
                         const float* __restrict__ W5, const float* __restrict__ b5,
                         float* __restrict__ K2, float* __restrict__ K3,
                         float* __restrict__ C4, float* __restrict__ C5) {
  int b = blockIdx.x >> 4, c = blockIdx.x & 15;
  int t0 = c * 8;
  int nt = (t0 + 8 <= T) ? 8 : (T - t0);
  int j = threadIdx.x;
  __shared__ float lp[8][DK], itv[8][DK], lc[8][DK], en[8][DK];
  for (int i = 0; i < nt; ++i) {
    int bs = b * S + t0 + i;
    lp[i][j]  = (t0 + i == 0) ? 0.0f : AL[(bs - 1) * DK + j];
    lc[i][j]  = AL[bs * DK + j];
    itv[i][j] = it_w[its[bs] * DK + j];
    en[i][j]  = e_w[qs[bs + 1] * DK + j];
  }
  __syncthreads();
  float a2[8], a3[8], a4[8], a5[8];
  float v2 = b2[j], v3 = b3[j], v4 = b4[j], v5 = b5[j];
#pragma unroll
  for (int i = 0; i < 8; ++i) { a2[i] = v2; a3[i] = v3; a4[i] = v4; a5[i] = v5; }
#pragma unroll 2
  for (int k = 0; k < DK; ++k) {
    float w2a = W2[k * DK + j], w2b = W2[(DK + k) * DK + j], w2c = W2[(2 * DK + k) * DK + j];
    float w3a = W3[k * DK + j], w3b = W3[(DK + k) * DK + j], w3c = W3[(2 * DK + k) * DK + j];
    float w4c = W4[(2 * DK + k) * DK + j];
    float w5a = W5[k * DK + j];
#pragma unroll
    for (int i = 0; i < 8; ++i) {
      float vlp = lp[i][k], vit = itv[i][k], vlc = lc[i][k], ven = en[i][k];
      a2[i] = fmaf(vlp, w2a, a2[i]); a2[i] = fmaf(vit, w2b, a2[i]); a2[i] = fmaf(vlc, w2c, a2[i]);
      a3[i] = fmaf(vlp, w3a, a3[i]); a3[i] = fmaf(vit, w3b, a3[i]); a3[i] = fmaf(vlc, w3c, a3[i]);
      a4[i] = fmaf(vit, w4c, a4[i]);
      a5[i] = fmaf(ven, w5a, a5[i]);
    }
  }
  for (int i = 0; i < nt; ++i) {
    int o = (b * T + t0 + i) * DK + j;
    K2[o] = a2[i]; K3[o] = a3[i]; C4[o] = a4[i]; C5[o] = a5[i];
  }
}

// ---------------------------------------------------------------------------
// Kernel 3: scan. 1 block/batch, 512 threads = 8 waves (wj = w&3, wn = w>>2).
// R7 structure (proven 553us). R9 deltas: W4b as f32 in conflict-free
// [kcc][col][4] LDS layout (removes 64 bf16-unpack shifts from A2),
// s_setprio around the MFMA cluster. Two barriers per step:
//   [ M || A1 || C(prev) ]  b1  [ prefetch; A2 (wave-local); B2 ]  b3
// ---------------------------------------------------------------------------
__global__ __launch_bounds__(512)
void k_scan(const int* __restrict__ qs,
            const float* __restrict__ qmat,
            const float* __restrict__ h0,
            const float* __restrict__ K2, const float* __restrict__ K3,
            const float* __restrict__ C4, const float* __restrict__ C5,
            const float* __restrict__ W2, const float* __restrict__ W3,
            const float* __restrict__ W4, const float* __restrict__ W5,
            float* __restrict__ out) {
  const int b   = blockIdx.x;
  const int tid = threadIdx.x;
  const int w   = tid >> 6;
  const int l   = tid & 63;
  const int l15 = l & 15;
  const int g   = l >> 4;          // 0..3
  const int wj  = w & 3;           // j-block of 32 cols
  const int wn  = w >> 2;          // 0..1: n-tiles 4wn..4wn+3
  const int gc  = 16 * w + l15;    // A1/C output column
  const int kb  = 32 * g;          // A1/C contraction base
  const int ac  = 32 * wj + (l & 31);  // A2 column
  const int akb = (l >> 5) * 64;       // A2 k-half base

  __shared__ alignas(16) unsigned short hBH[14336];        // h bf16, frag order (7 n-tiles)
  __shared__ alignas(16) float          W4F[32 * 132 * 4]; // W4b^T f32: [kcc][col][4]
  __shared__ alignas(16) unsigned short W5X[16 * 132 * 8]; // W5b^T bf16: [kc][col][8]
  __shared__ alignas(16) float sLG[144];
  __shared__ alignas(16) float sHT[2][144];                // h_tilde double buffer
  __shared__ alignas(16) float sQ[2][DK];
  __shared__ float sY[8];

  const float* W2d = W2 + 3 * DK * DK;
  const float* W3d = W3 + 3 * DK * DK;
  const float* W4a = W4;
  const float* W4b = W4 + DK * DK;
  const float* W5b = W5 + DK * DK;

  // ---- per-lane f32 weights for A1 (loop-invariant)
  float w2r[32], w3r[32];
#pragma unroll
  for (int kk = 0; kk < 32; ++kk) {
    w2r[kk] = W2d[(kb + kk) * DK + gc];
    w3r[kk] = W3d[(kb + kk) * DK + gc];
  }

  // ---- W4b (f32) / W5b (bf16) -> LDS in conflict-free layouts
  for (int i = tid; i < DK * DK; i += 512) {
    int k = i >> 7, j = i & 127;
    W4F[((k >> 2) * 132 + j) * 4 + (k & 3)] = W4b[i];
    W5X[((k >> 3) * 132 + j) * 8 + (k & 7)] = f2bf(W5b[i]);
  }

  // ---- A-fragments: A = W4a^T (bf16), 2 j-tiles per wave
  bf16x8 afr[2][4];
#pragma unroll
  for (int jt = 0; jt < 2; ++jt) {
    int j = 32 * wj + 16 * jt + l15;
#pragma unroll
    for (int ks = 0; ks < 4; ++ks) {
      bf16x8 v;
#pragma unroll
      for (int e = 0; e < 8; ++e) v[e] = (short)f2bf(W4a[(ks * 32 + g * 8 + e) * DK + j]);
      afr[jt][ks] = v;
    }
  }

  if (tid < DK) sQ[0][tid] = (tid < NC) ? qmat[qs[b * S] * NC + tid] : 0.0f;
  if (tid == 0) out[b * S] = 0.0f;
  if (tid < 144) { sHT[0][tid] = 0.0f; sHT[1][tid] = 0.0f; }

  // ---- init h registers (C layout) + fragment-order bf16 LDS
  float hold[2][4][4];
#pragma unroll
  for (int jt = 0; jt < 2; ++jt) {
    int j4 = 32 * wj + 16 * jt + 4 * g;
    int ks = j4 >> 5, lg = (j4 >> 3) & 3;
#pragma unroll
    for (int nt = 0; nt < 4; ++nt) {
      int ntg = 4 * wn + nt;
      if (ntg == 7) {
#pragma unroll
        for (int r = 0; r < 4; ++r) hold[jt][nt][r] = 0.0f;
        continue;
      }
      int n = 16 * ntg + l15;
      float x0 = (n < NC) ? h0[n * DK + j4 + 0] : 0.0f;
      float x1 = (n < NC) ? h0[n * DK + j4 + 1] : 0.0f;
      float x2 = (n < NC) ? h0[n * DK + j4 + 2] : 0.0f;
      float x3 = (n < NC) ? h0[n * DK + j4 + 3] : 0.0f;
      hold[jt][nt][0] = x0; hold[jt][nt][1] = x1;
      hold[jt][nt][2] = x2; hold[jt][nt][3] = x3;
      uint2 vh;
      vh.x = pkrta(x0, x1); vh.y = pkrta(x2, x3);
      int idx = ((ntg * 4 + ks) * 64 + (lg << 4) + l15) * 8 + ((j4 & 4) ? 4 : 0);
      *(uint2*)&hBH[idx] = vh;
    }
  }
  __syncthreads();

  // ---- h_tilde0 -> sHT[0]
  {
#pragma unroll
    for (int jt = 0; jt < 2; ++jt) {
      int j4 = 32 * wj + 16 * jt + 4 * g;
      float htp[4] = {0.f, 0.f, 0.f, 0.f};
#pragma unroll
      for (int nt = 0; nt < 4; ++nt) {
        int ntg = 4 * wn + nt;
        if (ntg == 7) continue;
        int n = 16 * ntg + l15;
        float qe = sQ[0][n];
#pragma unroll
        for (int r = 0; r < 4; ++r) htp[r] = fmaf(qe, hold[jt][nt][r], htp[r]);
      }
#pragma unroll
      for (int r = 0; r < 4; ++r) {
        float v = htp[r];
        v += __shfl_xor(v, 1, 64); v += __shfl_xor(v, 2, 64);
        v += __shfl_xor(v, 4, 64); v += __shfl_xor(v, 8, 64);
        if (l15 == 0) atomicAdd(&sHT[0][pk(j4 + r)], v);
      }
    }
  }
  __syncthreads();

  // ---- prefetch registers
  float k2v = K2[(b * T) * DK + gc], k3v = K3[(b * T) * DK + gc];
  float c4_pf = C4[(b * T) * DK + ac];
  float c5_pf = C5[(b * T) * DK + gc];
  float c5_use = 0.0f;
  float qnew = (tid < NC) ? qmat[qs[b * S + 1] * NC + tid] : 0.0f;

  for (int t = 0; t < T; ++t) {
    const int cur = t & 1, nxt = cur ^ 1;

    // ================= pre-b1: M || A1 || C(prev) =================

    // ---- Phase M: dot = W4a^T x h^T (single bf16)
    f32x4 acc[2][4];
#pragma unroll
    for (int jt = 0; jt < 2; ++jt)
#pragma unroll
      for (int nt = 0; nt < 4; ++nt) acc[jt][nt] = (f32x4){0.f, 0.f, 0.f, 0.f};
    __builtin_amdgcn_s_setprio(1);
#pragma unroll
    for (int nt = 0; nt < 4; ++nt) {
      int ntg = 4 * wn + nt;
      if (ntg == 7) continue;
      bf16x8 bh[4];
#pragma unroll
      for (int ks = 0; ks < 4; ++ks)
        bh[ks] = *(const bf16x8*)&hBH[(ntg * 4 + ks) * 512 + l * 8];
#pragma unroll
      for (int ks = 0; ks < 4; ++ks)
#pragma unroll
        for (int jt = 0; jt < 2; ++jt)
          acc[jt][nt] = __builtin_amdgcn_mfma_f32_16x16x32_bf16(afr[jt][ks], bh[ks], acc[jt][nt], 0, 0, 0);
    }
    __builtin_amdgcn_s_setprio(0);

    // ---- Phase C (for step t-1): y = mean(sigmoid(C5 + h_tilde@W5b))
    if (t > 0) {
      float pa = 0.f, pb = 0.f;
#pragma unroll
      for (int m = 0; m < 4; ++m) {
        u16x8 wv = *(const u16x8*)&W5X[(((g << 2) + m) * 132 + gc) * 8];
        float4 h0v = *(const float4*)&sHT[cur][36 * g + 8 * m];
        float4 h1v = *(const float4*)&sHT[cur][36 * g + 8 * m + 4];
        pa = fmaf(h0v.x, bfhi(wv[0]), pa);
        pb = fmaf(h0v.y, bfhi(wv[1]), pb);
        pa = fmaf(h0v.z, bfhi(wv[2]), pa);
        pb = fmaf(h0v.w, bfhi(wv[3]), pb);
        pa = fmaf(h1v.x, bfhi(wv[4]), pa);
        pb = fmaf(h1v.y, bfhi(wv[5]), pb);
        pa = fmaf(h1v.z, bfhi(wv[6]), pa);
        pb = fmaf(h1v.w, bfhi(wv[7]), pb);
      }
      float p = pa + pb;
      p += __shfl_xor(p, 16, 64); p += __shfl_xor(p, 32, 64);
      float u = sigm(c5_use + p);
      u += __shfl_xor(u, 1, 64); u += __shfl_xor(u, 2, 64);
      u += __shfl_xor(u, 4, 64); u += __shfl_xor(u, 8, 64);
      if (l == 0) sY[w] = u;
    }

    // ---- Phase A1: LG from h_tilde (weights in VGPRs)
    {
      float p2a = 0.f, p2b = 0.f, p3a = 0.f, p3b = 0.f;
#pragma unroll
      for (int m = 0; m < 8; ++m) {
        float4 hv = *(const float4*)&sHT[cur][36 * g + 4 * m];
        p2a = fmaf(hv.x, w2r[4 * m + 0], p2a); p3a = fmaf(hv.x, w3r[4 * m + 0], p3a);
        p2b = fmaf(hv.y, w2r[4 * m + 1], p2b); p3b = fmaf(hv.y, w3r[4 * m + 1], p3b);
        p2a = fmaf(hv.z, w2r[4 * m + 2], p2a); p3a = fmaf(hv.z, w3r[4 * m + 2], p3a);
        p2b = fmaf(hv.w, w2r[4 * m + 3], p2b); p3b = fmaf(hv.w, w3r[4 * m + 3], p3b);
      }
      float p2 = p2a + p2b, p3 = p3a + p3b;
      p2 += __shfl_xor(p2, 16, 64); p2 += __shfl_xor(p2, 32, 64);
      p3 += __shfl_xor(p3, 16, 64); p3 += __shfl_xor(p3, 32, 64);
      if (l < 16) {
        float x2 = k2v + p2, x3 = k3v + p3;
        sLG[pk(gc)] = sigm(x3) * (tanh_fast(x2) + 1.0f) * 0.5f;
      }
      if (tid < DK) {
        sQ[nxt][tid] = qnew;
        sHT[nxt][pk(tid)] = 0.0f;     // zero the buffer B2 will accumulate into
      }
    }
    __syncthreads();                                  // b1

    // ================= post-b1: y-write; prefetch; A2; B2 =================

    if (t > 0 && tid == 0) {
      float s = sY[0] + sY[1] + sY[2] + sY[3] + sY[4] + sY[5] + sY[6] + sY[7];
      out[b * S + t] = s * (1.0f / DK);
    }

    // shift + issue prefetches for next iteration (overlap with A2+B2)
    float c4_use = c4_pf;
    c5_use = c5_pf;
    {
      int tn  = (t + 1 < T) ? (t + 1) : (T - 1);
      int btn = (b * T + tn) * DK;
      k2v = K2[btn + gc]; k3v = K3[btn + gc];
      c4_pf = C4[btn + ac]; c5_pf = C5[btn + gc];
      int rq = (t + 2 < S) ? (t + 2) : (S - 1);
      qnew = (tid < NC) ? qmat[qs[b * S + rq] * NC + tid] : 0.0f;
    }

    // ---- Phase A2 (wave-local): V[ac] = C4 + LG @ W4b (f32 weights, no unpack)
    float vv[2][4];
    {
      float pa = 0.f, pb = 0.f;
#pragma unroll
      for (int mm = 0; mm < 8; ++mm) {
        int kcc = (akb >> 2) + 2 * mm;
        float4 w0 = *(const float4*)&W4F[(kcc * 132 + ac) * 4];
        float4 w1 = *(const float4*)&W4F[((kcc + 1) * 132 + ac) * 4];
        float4 a0 = *(const float4*)&sLG[pk(akb + 8 * mm)];
        float4 a1 = *(const float4*)&sLG[pk(akb + 8 * mm + 4)];
        pa = fmaf(a0.x, w0.x, pa);
        pb = fmaf(a0.y, w0.y, pb);
        pa = fmaf(a0.z, w0.z, pa);
        pb = fmaf(a0.w, w0.w, pb);
        pa = fmaf(a1.x, w1.x, pa);
        pb = fmaf(a1.y, w1.y, pb);
        pa = fmaf(a1.z, w1.z, pa);
        pb = fmaf(a1.w, w1.w, pb);
      }
      float V = pa + pb;
      V += __shfl_xor(V, 32, 64);
      V += c4_use;
#pragma unroll
      for (int jt = 0; jt < 2; ++jt)
#pragma unroll
        for (int r = 0; r < 4; ++r)
          vv[jt][r] = __shfl(V, 16 * jt + 4 * g + r, 64);
    }

    // ---- Phase B2: gamma_f, h update, writeback, h_tilde partials
    {
#pragma unroll
      for (int jt = 0; jt < 2; ++jt) {
        int j4 = 32 * wj + 16 * jt + 4 * g;
        float4 a = *(const float4*)&sLG[pk(j4)];
        float lgv[4] = {a.x, a.y, a.z, a.w};
        float htpr[4] = {0.f, 0.f, 0.f, 0.f};
        int ks = j4 >> 5, lg = (j4 >> 3) & 3;
#pragma unroll
        for (int nt = 0; nt < 4; ++nt) {
          int ntg = 4 * wn + nt;
          if (ntg == 7) continue;
          int n = 16 * ntg + l15;
          float qe = sQ[cur][n], qn = sQ[nxt][n];
          float hn[4];
#pragma unroll
          for (int r = 0; r < 4; ++r) {
            float gf = sigm(acc[jt][nt][r] + vv[jt][r]);
            hn[r] = fmaf(gf, hold[jt][nt][r], qe * lgv[r]);
            hold[jt][nt][r] = hn[r];
            htpr[r] = fmaf(qn, hn[r], htpr[r]);
          }
          uint2 vh;
          vh.x = pkrta(hn[0], hn[1]); vh.y = pkrta(hn[2], hn[3]);
          int idx = ((ntg * 4 + ks) * 64 + (lg << 4) + l15) * 8 + ((j4 & 4) ? 4 : 0);
          *(uint2*)&hBH[idx] = vh;
        }
#pragma unroll
        for (int r = 0; r < 4; ++r) {
          float v = htpr[r];
          v += __shfl_xor(v, 1, 64); v += __shfl_xor(v, 2, 64);
          v += __shfl_xor(v, 4, 64); v += __shfl_xor(v, 8, 64);
          if (l15 == 0) atomicAdd(&sHT[nxt][pk(j4 + r)], v);
        }
      }
    }
    __syncthreads();                                  // b3
  }

  // ---- final C for step T-1 + y write
  {
    const int fin = T & 1;
    float pa = 0.f, pb = 0.f;
#pragma unroll
    for (int m = 0; m < 4; ++m) {
      u16x8 wv = *(const u16x8*)&W5X[(((g << 2) + m) * 132 + gc) * 8];
      float4 h0v = *(const float4*)&sHT[fin][36 * g + 8 * m];
      float4 h1v = *(const float4*)&sHT[fin][36 * g + 8 * m + 4];
      pa = fmaf(h0v.x, bfhi(wv[0]), pa);
      pb = fmaf(h0v.y, bfhi(wv[1]), pb);
      pa = fmaf(h0v.z, bfhi(wv[2]), pa);
      pb = fmaf(h0v.w, bfhi(wv[3]), pb);
      pa = fmaf(h1v.x, bfhi(wv[4]), pa);
      pb = fmaf(h1v.y, bfhi(wv[5]), pb);
      pa = fmaf(h1v.z, bfhi(wv[6]), pa);
      pb = fmaf(h1v.w, bfhi(wv[7]), pb);
    }
    float p = pa + pb;
    p += __shfl_xor(p, 16, 64); p += __shfl_xor(p, 32, 64);
    float u = sigm(c5_use + p);
    u += __shfl_xor(u, 1, 64); u += __shfl_xor(u, 2, 64);
    u += __shfl_xor(u, 4, 64); u += __shfl_xor(u, 8, 64);
    if (l == 0) sY[w] = u;
  }
  __syncthreads();
  if (tid == 0) {
    float s = sY[0] + sY[1] + sY[2] + sY[3] + sY[4] + sY[5] + sY[6] + sY[7];
    out[b * S + T] = s * (1.0f / DK);
  }
}

extern "C" void kernel_launch(void* const* d_in, const int* in_sizes, int n_in,
                              void* d_out, int out_size, void* d_ws, size_t ws_size,
                              hipStream_t stream) {
  const int*   qs   = (const int*)d_in[0];
  const int*   ats  = (const int*)d_in[1];
  const int*   its  = (const int*)d_in[2];
  const float* corr = (const float*)d_in[3];
  const float* qmat = (const float*)d_in[4];
  const float* h0   = (const float*)d_in[5];
  const float* e_w  = (const float*)d_in[6];
  const float* at_w = (const float*)d_in[7];
  const float* it_w = (const float*)d_in[8];
  const float* W1 = (const float*)d_in[9];  const float* b1 = (const float*)d_in[10];
  const float* W2 = (const float*)d_in[11]; const float* b2 = (const float*)d_in[12];
  const float* W3 = (const float*)d_in[13]; const float* b3 = (const float*)d_in[14];
  const float* W4 = (const float*)d_in[15]; const float* b4 = (const float*)d_in[16];
  const float* W5 = (const float*)d_in[17]; const float* b5 = (const float*)d_in[18];
  float* out = (float*)d_out;

  float* AL = (float*)d_ws;              // B*S*DK
  float* K2 = AL + B * S * DK;           // B*T*DK
  float* K3 = K2 + B * T * DK;
  float* C4 = K3 + B * T * DK;
  float* C5 = C4 + B * T * DK;

  k_all_learning<<<dim3(B * 16), dim3(DK), 0, stream>>>(qs, ats, corr, e_w, at_w, W1, b1, AL);
  k_consts<<<dim3(B * 16), dim3(DK), 0, stream>>>(qs, its, it_w, e_w, AL,
                                                  W2, b2, W3, b3, W4, b4, W5, b5,
                                                  K2, K3, C4, C5);
  k_scan<<<dim3(B), dim3(512), 0, stream>>>(qs, qmat, h0, K2, K3, C4, C5,
                                            W2, W3, W4, W5, out);
}

// Round 10
// 608.194 us; speedup vs baseline: 1.7430x; 1.0341x over previous
//
#include <hip/hip_runtime.h>

constexpr int B  = 16;
constexpr int S  = 128;
constexpr int NC = 100;
constexpr int DK = 128;
constexpr int T  = S - 1;

typedef __attribute__((ext_vector_type(8))) short bf16x8;
typedef __attribute__((ext_vector_type(8))) unsigned short u16x8;
typedef __attribute__((ext_vector_type(4))) float f32x4;

__device__ __forceinline__ float sigm(float x) {
  return __builtin_amdgcn_rcpf(1.0f + __expf(-x));
}
__device__ __forceinline__ float tanh_fast(float x) {
  return 2.0f * __builtin_amdgcn_rcpf(1.0f + __expf(-2.0f * x)) - 1.0f;
}
__device__ __forceinline__ unsigned short f2bf(float x) {   // RNE f32 -> bf16
  unsigned u = __float_as_uint(x);
  u += 0x7fff + ((u >> 16) & 1);
  return (unsigned short)(u >> 16);
}
// round-half-up bf16 pack: hi16(a+0.5ulp) low, hi16(b+0.5ulp) high
__device__ __forceinline__ unsigned pkrta(float a, float b) {
  unsigned ua = __float_as_uint(a) + 0x8000u;
  unsigned ub = __float_as_uint(b) + 0x8000u;
  return __builtin_amdgcn_perm(ub, ua, 0x07060302u);
}
__device__ __forceinline__ float bfhi(unsigned short v) {
  return __uint_as_float(((unsigned)v) << 16);
}
// padded index: +4 words after each 32-float chunk
__device__ __forceinline__ int pk(int k) { return k + ((k >> 5) << 2); }

// ---------------------------------------------------------------------------
// Kernel 1: AL[b,s,:] = [e_emb, at_emb, corr] @ W1 + b1   (8 s per block)
// ---------------------------------------------------------------------------
__global__ void k_all_learning(const int* __restrict__ qs, const int* __restrict__ ats,
                               const float* __restrict__ corr,
                               const float* __restrict__ e_w, const float* __restrict__ at_w,
                               const float* __restrict__ W1, const float* __restrict__ b1,
                               float* __restrict__ AL) {
  int b = blockIdx.x >> 4, c = blockIdx.x & 15;
  int s0 = c * 8;
  int j = threadIdx.x;
  __shared__ float ve[8][DK], va[8][DK];
  __shared__ float cr[8];
#pragma unroll
  for (int i = 0; i < 8; ++i) {
    int bs = b * S + s0 + i;
    ve[i][j] = e_w[qs[bs] * DK + j];
    va[i][j] = at_w[ats[bs] * DK + j];
    if (j == 0) cr[i] = corr[bs];
  }
  __syncthreads();
  float acc[8];
  float cs = 0.0f;
#pragma unroll 4
  for (int k = 0; k < DK; ++k) cs += W1[(2 * DK + k) * DK + j];
  float bj = b1[j];
#pragma unroll
  for (int i = 0; i < 8; ++i) acc[i] = bj + cr[i] * cs;
#pragma unroll 2
  for (int k = 0; k < DK; ++k) {
    float we = W1[k * DK + j];
    float wa = W1[(DK + k) * DK + j];
#pragma unroll
    for (int i = 0; i < 8; ++i) {
      acc[i] = fmaf(ve[i][k], we, acc[i]);
      acc[i] = fmaf(va[i][k], wa, acc[i]);
    }
  }
#pragma unroll
  for (int i = 0; i < 8; ++i) AL[(b * S + s0 + i) * DK + j] = acc[i];
}

// ---------------------------------------------------------------------------
// Kernel 2: per (b,t): K2/K3 (x4@W2/W3 minus h_tilde part), C4, C5.
// ---------------------------------------------------------------------------
__global__ void k_consts(const int* __restrict__ qs, const int* __restrict__ its,
                         const float* __restrict__ it_w, const float* __restrict__ e_w,
                         const float* __restrict__ AL,
                         const float* __restrict__ W2, const float* __restrict__ b2,
                         const float* __restrict__ W3, const float* __restrict__ b3,
                         const float* __restrict__ W4, const float* __restrict__ b4,
                         const float* __restrict__ W5, const float* __restrict__ b5,
                         float* __restrict__ K2, float* __restrict__ K3,
                         float* __restrict__ C4, float* __restrict__ C5) {
  int b = blockIdx.x >> 4, c = blockIdx.x & 15;
  int t0 = c * 8;
  int nt = (t0 + 8 <= T) ? 8 : (T - t0);
  int j = threadIdx.x;
  __shared__ float lp[8][DK], itv[8][DK], lc[8][DK], en[8][DK];
  for (int i = 0; i < nt; ++i) {
    int bs = b * S + t0 + i;
    lp[i][j]  = (t0 + i == 0) ? 0.0f : AL[(bs - 1) * DK + j];
    lc[i][j]  = AL[bs * DK + j];
    itv[i][j] = it_w[its[bs] * DK + j];
    en[i][j]  = e_w[qs[bs + 1] * DK + j];
  }
  __syncthreads();
  float a2[8], a3[8], a4[8], a5[8];
  float v2 = b2[j], v3 = b3[j], v4 = b4[j], v5 = b5[j];
#pragma unroll
  for (int i = 0; i < 8; ++i) { a2[i] = v2; a3[i] = v3; a4[i] = v4; a5[i] = v5; }
#pragma unroll 2
  for (int k = 0; k < DK; ++k) {
    float w2a = W2[k * DK + j], w2b = W2[(DK + k) * DK + j], w2c = W2[(2 * DK + k) * DK + j];
    float w3a = W3[k * DK + j], w3b = W3[(DK + k) * DK + j], w3c = W3[(2 * DK + k) * DK + j];
    float w4c = W4[(2 * DK + k) * DK + j];
    float w5a = W5[k * DK + j];
#pragma unroll
    for (int i = 0; i < 8; ++i) {
      float vlp = lp[i][k], vit = itv[i][k], vlc = lc[i][k], ven = en[i][k];
      a2[i] = fmaf(vlp, w2a, a2[i]); a2[i] = fmaf(vit, w2b, a2[i]); a2[i] = fmaf(vlc, w2c, a2[i]);
      a3[i] = fmaf(vlp, w3a, a3[i]); a3[i] = fmaf(vit, w3b, a3[i]); a3[i] = fmaf(vlc, w3c, a3[i]);
      a4[i] = fmaf(vit, w4c, a4[i]);
      a5[i] = fmaf(ven, w5a, a5[i]);
    }
  }
  for (int i = 0; i < nt; ++i) {
    int o = (b * T + t0 + i) * DK + j;
    K2[o] = a2[i]; K3[o] = a3[i]; C4[o] = a4[i]; C5[o] = a5[i];
  }
}

// ---------------------------------------------------------------------------
// Kernel 3: scan. 1 block/batch, 512 threads = 8 waves (wj = w&3, wn = w>>2).
// h single bf16 (round-half-up). W4b AND W5b in conflict-free [kc][col][8]
// LDS layouts (no big per-lane weight arrays beyond w2r/w3r -> no spills).
// LDS ~99 KB -> exactly 1 block/CU. Two barriers per step:
//   [ M || A1 || C(prev) ]  b1  [ prefetch; A2 (wave-local); B2 ]  b3
// ---------------------------------------------------------------------------
__global__ __launch_bounds__(512)
void k_scan(const int* __restrict__ qs,
            const float* __restrict__ qmat,
            const float* __restrict__ h0,
            const float* __restrict__ K2, const float* __restrict__ K3,
            const float* __restrict__ C4, const float* __restrict__ C5,
            const float* __restrict__ W2, const float* __restrict__ W3,
            const float* __restrict__ W4, const float* __restrict__ W5,
            float* __restrict__ out) {
  const int b   = blockIdx.x;
  const int tid = threadIdx.x;
  const int w   = tid >> 6;
  const int l   = tid & 63;
  const int l15 = l & 15;
  const int g   = l >> 4;          // 0..3
  const int wj  = w & 3;           // j-block of 32 cols
  const int wn  = w >> 2;          // 0..1: n-tiles 4wn..4wn+3
  const int gc  = 16 * w + l15;    // A1/C output column
  const int kb  = 32 * g;          // A1/C contraction base
  const int ac  = 32 * wj + (l & 31);  // A2 column
  const int akb = (l >> 5) * 64;       // A2 k-half base

  __shared__ alignas(16) unsigned short hBH[14336];        // h bf16, frag order (7 n-tiles)
  __shared__ alignas(16) unsigned short W4X[16 * 132 * 8]; // W4b^T bf16: [kc][col][8]
  __shared__ alignas(16) unsigned short W5X[16 * 132 * 8]; // W5b^T bf16: [kc][col][8]
  __shared__ alignas(16) float sLG[144];
  __shared__ alignas(16) float sHT[2][144];                // h_tilde double buffer
  __shared__ alignas(16) float sQ[2][DK];
  __shared__ float sY[8];

  const float* W2d = W2 + 3 * DK * DK;
  const float* W3d = W3 + 3 * DK * DK;
  const float* W4a = W4;
  const float* W4b = W4 + DK * DK;
  const float* W5b = W5 + DK * DK;

  // ---- per-lane f32 weights for A1 (loop-invariant)
  float w2r[32], w3r[32];
#pragma unroll
  for (int kk = 0; kk < 32; ++kk) {
    w2r[kk] = W2d[(kb + kk) * DK + gc];
    w3r[kk] = W3d[(kb + kk) * DK + gc];
  }

  // ---- W4b / W5b -> LDS in [kc][col][8] layout (conflict-free b128 reads)
  for (int i = tid; i < DK * DK; i += 512) {
    int k = i >> 7, j = i & 127;
    int o = ((k >> 3) * 132 + j) * 8 + (k & 7);
    W4X[o] = f2bf(W4b[i]);
    W5X[o] = f2bf(W5b[i]);
  }

  // ---- A-fragments: A = W4a^T (bf16), 2 j-tiles per wave
  bf16x8 afr[2][4];
#pragma unroll
  for (int jt = 0; jt < 2; ++jt) {
    int j = 32 * wj + 16 * jt + l15;
#pragma unroll
    for (int ks = 0; ks < 4; ++ks) {
      bf16x8 v;
#pragma unroll
      for (int e = 0; e < 8; ++e) v[e] = (short)f2bf(W4a[(ks * 32 + g * 8 + e) * DK + j]);
      afr[jt][ks] = v;
    }
  }

  if (tid < DK) sQ[0][tid] = (tid < NC) ? qmat[qs[b * S] * NC + tid] : 0.0f;
  if (tid == 0) out[b * S] = 0.0f;
  if (tid < 144) { sHT[0][tid] = 0.0f; sHT[1][tid] = 0.0f; }

  // ---- init h registers (C layout) + fragment-order bf16 LDS
  float hold[2][4][4];
#pragma unroll
  for (int jt = 0; jt < 2; ++jt) {
    int j4 = 32 * wj + 16 * jt + 4 * g;
    int ks = j4 >> 5, lg = (j4 >> 3) & 3;
#pragma unroll
    for (int nt = 0; nt < 4; ++nt) {
      int ntg = 4 * wn + nt;
      if (ntg == 7) {
#pragma unroll
        for (int r = 0; r < 4; ++r) hold[jt][nt][r] = 0.0f;
        continue;
      }
      int n = 16 * ntg + l15;
      float x0 = (n < NC) ? h0[n * DK + j4 + 0] : 0.0f;
      float x1 = (n < NC) ? h0[n * DK + j4 + 1] : 0.0f;
      float x2 = (n < NC) ? h0[n * DK + j4 + 2] : 0.0f;
      float x3 = (n < NC) ? h0[n * DK + j4 + 3] : 0.0f;
      hold[jt][nt][0] = x0; hold[jt][nt][1] = x1;
      hold[jt][nt][2] = x2; hold[jt][nt][3] = x3;
      uint2 vh;
      vh.x = pkrta(x0, x1); vh.y = pkrta(x2, x3);
      int idx = ((ntg * 4 + ks) * 64 + (lg << 4) + l15) * 8 + ((j4 & 4) ? 4 : 0);
      *(uint2*)&hBH[idx] = vh;
    }
  }
  __syncthreads();

  // ---- h_tilde0 -> sHT[0]
  {
#pragma unroll
    for (int jt = 0; jt < 2; ++jt) {
      int j4 = 32 * wj + 16 * jt + 4 * g;
      float htp[4] = {0.f, 0.f, 0.f, 0.f};
#pragma unroll
      for (int nt = 0; nt < 4; ++nt) {
        int ntg = 4 * wn + nt;
        if (ntg == 7) continue;
        int n = 16 * ntg + l15;
        float qe = sQ[0][n];
#pragma unroll
        for (int r = 0; r < 4; ++r) htp[r] = fmaf(qe, hold[jt][nt][r], htp[r]);
      }
#pragma unroll
      for (int r = 0; r < 4; ++r) {
        float v = htp[r];
        v += __shfl_xor(v, 1, 64); v += __shfl_xor(v, 2, 64);
        v += __shfl_xor(v, 4, 64); v += __shfl_xor(v, 8, 64);
        if (l15 == 0) atomicAdd(&sHT[0][pk(j4 + r)], v);
      }
    }
  }
  __syncthreads();

  // ---- prefetch registers
  float k2v = K2[(b * T) * DK + gc], k3v = K3[(b * T) * DK + gc];
  float c4_pf = C4[(b * T) * DK + ac];
  float c5_pf = C5[(b * T) * DK + gc];
  float c5_use = 0.0f;
  float qnew = (tid < NC) ? qmat[qs[b * S + 1] * NC + tid] : 0.0f;

  for (int t = 0; t < T; ++t) {
    const int cur = t & 1, nxt = cur ^ 1;

    // ================= pre-b1: M || A1 || C(prev) =================

    // ---- Phase M: dot = W4a^T x h^T (single bf16)
    f32x4 acc[2][4];
#pragma unroll
    for (int jt = 0; jt < 2; ++jt)
#pragma unroll
      for (int nt = 0; nt < 4; ++nt) acc[jt][nt] = (f32x4){0.f, 0.f, 0.f, 0.f};
#pragma unroll
    for (int nt = 0; nt < 4; ++nt) {
      int ntg = 4 * wn + nt;
      if (ntg == 7) continue;
      bf16x8 bh[4];
#pragma unroll
      for (int ks = 0; ks < 4; ++ks)
        bh[ks] = *(const bf16x8*)&hBH[(ntg * 4 + ks) * 512 + l * 8];
#pragma unroll
      for (int ks = 0; ks < 4; ++ks)
#pragma unroll
        for (int jt = 0; jt < 2; ++jt)
          acc[jt][nt] = __builtin_amdgcn_mfma_f32_16x16x32_bf16(afr[jt][ks], bh[ks], acc[jt][nt], 0, 0, 0);
    }

    // ---- Phase C (for step t-1): y = mean(sigmoid(C5 + h_tilde@W5b))
    if (t > 0) {
      float pa = 0.f, pb = 0.f;
#pragma unroll
      for (int m = 0; m < 4; ++m) {
        u16x8 wv = *(const u16x8*)&W5X[(((g << 2) + m) * 132 + gc) * 8];
        float4 h0v = *(const float4*)&sHT[cur][36 * g + 8 * m];
        float4 h1v = *(const float4*)&sHT[cur][36 * g + 8 * m + 4];
        pa = fmaf(h0v.x, bfhi(wv[0]), pa);
        pb = fmaf(h0v.y, bfhi(wv[1]), pb);
        pa = fmaf(h0v.z, bfhi(wv[2]), pa);
        pb = fmaf(h0v.w, bfhi(wv[3]), pb);
        pa = fmaf(h1v.x, bfhi(wv[4]), pa);
        pb = fmaf(h1v.y, bfhi(wv[5]), pb);
        pa = fmaf(h1v.z, bfhi(wv[6]), pa);
        pb = fmaf(h1v.w, bfhi(wv[7]), pb);
      }
      float p = pa + pb;
      p += __shfl_xor(p, 16, 64); p += __shfl_xor(p, 32, 64);
      float u = sigm(c5_use + p);
      u += __shfl_xor(u, 1, 64); u += __shfl_xor(u, 2, 64);
      u += __shfl_xor(u, 4, 64); u += __shfl_xor(u, 8, 64);
      if (l == 0) sY[w] = u;
    }

    // ---- Phase A1: LG from h_tilde (weights in VGPRs)
    {
      float p2a = 0.f, p2b = 0.f, p3a = 0.f, p3b = 0.f;
#pragma unroll
      for (int m = 0; m < 8; ++m) {
        float4 hv = *(const float4*)&sHT[cur][36 * g + 4 * m];
        p2a = fmaf(hv.x, w2r[4 * m + 0], p2a); p3a = fmaf(hv.x, w3r[4 * m + 0], p3a);
        p2b = fmaf(hv.y, w2r[4 * m + 1], p2b); p3b = fmaf(hv.y, w3r[4 * m + 1], p3b);
        p2a = fmaf(hv.z, w2r[4 * m + 2], p2a); p3a = fmaf(hv.z, w3r[4 * m + 2], p3a);
        p2b = fmaf(hv.w, w2r[4 * m + 3], p2b); p3b = fmaf(hv.w, w3r[4 * m + 3], p3b);
      }
      float p2 = p2a + p2b, p3 = p3a + p3b;
      p2 += __shfl_xor(p2, 16, 64); p2 += __shfl_xor(p2, 32, 64);
      p3 += __shfl_xor(p3, 16, 64); p3 += __shfl_xor(p3, 32, 64);
      if (l < 16) {
        float x2 = k2v + p2, x3 = k3v + p3;
        sLG[pk(gc)] = sigm(x3) * (tanh_fast(x2) + 1.0f) * 0.5f;
      }
      if (tid < DK) {
        sQ[nxt][tid] = qnew;
        sHT[nxt][pk(tid)] = 0.0f;     // zero the buffer B2 will accumulate into
      }
    }
    __syncthreads();                                  // b1

    // ================= post-b1: y-write; prefetch; A2; B2 =================

    if (t > 0 && tid == 0) {
      float s = sY[0] + sY[1] + sY[2] + sY[3] + sY[4] + sY[5] + sY[6] + sY[7];
      out[b * S + t] = s * (1.0f / DK);
    }

    // shift + issue prefetches for next iteration (overlap with A2+B2)
    float c4_use = c4_pf;
    c5_use = c5_pf;
    {
      int tn  = (t + 1 < T) ? (t + 1) : (T - 1);
      int btn = (b * T + tn) * DK;
      k2v = K2[btn + gc]; k3v = K3[btn + gc];
      c4_pf = C4[btn + ac]; c5_pf = C5[btn + gc];
      int rq = (t + 2 < S) ? (t + 2) : (S - 1);
      qnew = (tid < NC) ? qmat[qs[b * S + rq] * NC + tid] : 0.0f;
    }

    // ---- Phase A2 (wave-local): V[ac] = C4 + LG @ W4b; distribute via shfl
    float vv[2][4];
    {
      float pa = 0.f, pb = 0.f;
#pragma unroll
      for (int mm = 0; mm < 8; ++mm) {
        int kc = (akb >> 3) + mm;
        u16x8 wv = *(const u16x8*)&W4X[(kc * 132 + ac) * 8];
        float4 a0 = *(const float4*)&sLG[pk(akb + 8 * mm)];
        float4 a1 = *(const float4*)&sLG[pk(akb + 8 * mm + 4)];
        pa = fmaf(a0.x, bfhi(wv[0]), pa);
        pb = fmaf(a0.y, bfhi(wv[1]), pb);
        pa = fmaf(a0.z, bfhi(wv[2]), pa);
        pb = fmaf(a0.w, bfhi(wv[3]), pb);
        pa = fmaf(a1.x, bfhi(wv[4]), pa);
        pb = fmaf(a1.y, bfhi(wv[5]), pb);
        pa = fmaf(a1.z, bfhi(wv[6]), pa);
        pb = fmaf(a1.w, bfhi(wv[7]), pb);
      }
      float V = pa + pb;
      V += __shfl_xor(V, 32, 64);
      V += c4_use;
#pragma unroll
      for (int jt = 0; jt < 2; ++jt)
#pragma unroll
        for (int r = 0; r < 4; ++r)
          vv[jt][r] = __shfl(V, 16 * jt + 4 * g + r, 64);
    }

    // ---- Phase B2: gamma_f, h update, writeback, h_tilde partials
    {
#pragma unroll
      for (int jt = 0; jt < 2; ++jt) {
        int j4 = 32 * wj + 16 * jt + 4 * g;
        float4 a = *(const float4*)&sLG[pk(j4)];
        float lgv[4] = {a.x, a.y, a.z, a.w};
        float htpr[4] = {0.f, 0.f, 0.f, 0.f};
        int ks = j4 >> 5, lg = (j4 >> 3) & 3;
#pragma unroll
        for (int nt = 0; nt < 4; ++nt) {
          int ntg = 4 * wn + nt;
          if (ntg == 7) continue;
          int n = 16 * ntg + l15;
          float qe = sQ[cur][n], qn = sQ[nxt][n];
          float hn[4];
#pragma unroll
          for (int r = 0; r < 4; ++r) {
            float gf = sigm(acc[jt][nt][r] + vv[jt][r]);
            hn[r] = fmaf(gf, hold[jt][nt][r], qe * lgv[r]);
            hold[jt][nt][r] = hn[r];
            htpr[r] = fmaf(qn, hn[r], htpr[r]);
          }
          uint2 vh;
          vh.x = pkrta(hn[0], hn[1]); vh.y = pkrta(hn[2], hn[3]);
          int idx = ((ntg * 4 + ks) * 64 + (lg << 4) + l15) * 8 + ((j4 & 4) ? 4 : 0);
          *(uint2*)&hBH[idx] = vh;
        }
#pragma unroll
        for (int r = 0; r < 4; ++r) {
          float v = htpr[r];
          v += __shfl_xor(v, 1, 64); v += __shfl_xor(v, 2, 64);
          v += __shfl_xor(v, 4, 64); v += __shfl_xor(v, 8, 64);
          if (l15 == 0) atomicAdd(&sHT[nxt][pk(j4 + r)], v);
        }
      }
    }
    __syncthreads();                                  // b3
  }

  // ---- final C for step T-1 + y write
  {
    const int fin = T & 1;
    float pa = 0.f, pb = 0.f;
#pragma unroll
    for (int m = 0; m < 4; ++m) {
      u16x8 wv = *(const u16x8*)&W5X[(((g << 2) + m) * 132 + gc) * 8];
      float4 h0v = *(const float4*)&sHT[fin][36 * g + 8 * m];
      float4 h1v = *(const float4*)&sHT[fin][36 * g + 8 * m + 4];
      pa = fmaf(h0v.x, bfhi(wv[0]), pa);
      pb = fmaf(h0v.y, bfhi(wv[1]), pb);
      pa = fmaf(h0v.z, bfhi(wv[2]), pa);
      pb = fmaf(h0v.w, bfhi(wv[3]), pb);
      pa = fmaf(h1v.x, bfhi(wv[4]), pa);
      pb = fmaf(h1v.y, bfhi(wv[5]), pb);
      pa = fmaf(h1v.z, bfhi(wv[6]), pa);
      pb = fmaf(h1v.w, bfhi(wv[7]), pb);
    }
    float p = pa + pb;
    p += __shfl_xor(p, 16, 64); p += __shfl_xor(p, 32, 64);
    float u = sigm(c5_use + p);
    u += __shfl_xor(u, 1, 64); u += __shfl_xor(u, 2, 64);
    u += __shfl_xor(u, 4, 64); u += __shfl_xor(u, 8, 64);
    if (l == 0) sY[w] = u;
  }
  __syncthreads();
  if (tid == 0) {
    float s = sY[0] + sY[1] + sY[2] + sY[3] + sY[4] + sY[5] + sY[6] + sY[7];
    out[b * S + T] = s * (1.0f / DK);
  }
}

extern "C" void kernel_launch(void* const* d_in, const int* in_sizes, int n_in,
                              void* d_out, int out_size, void* d_ws, size_t ws_size,
                              hipStream_t stream) {
  const int*   qs   = (const int*)d_in[0];
  const int*   ats  = (const int*)d_in[1];
  const int*   its  = (const int*)d_in[2];
  const float* corr = (const float*)d_in[3];
  const float* qmat = (const float*)d_in[4];
  const float* h0   = (const float*)d_in[5];
  const float* e_w  = (const float*)d_in[6];
  const float* at_w = (const float*)d_in[7];
  const float* it_w = (const float*)d_in[8];
  const float* W1 = (const float*)d_in[9];  const float* b1 = (const float*)d_in[10];
  const float* W2 = (const float*)d_in[11]; const float* b2 = (const float*)d_in[12];
  const float* W3 = (const float*)d_in[13]; const float* b3 = (const float*)d_in[14];
  const float* W4 = (const float*)d_in[15]; const float* b4 = (const float*)d_in[16];
  const float* W5 = (const float*)d_in[17]; const float* b5 = (const float*)d_in[18];
  float* out = (float*)d_out;

  float* AL = (float*)d_ws;              // B*S*DK
  float* K2 = AL + B * S * DK;           // B*T*DK
  float* K3 = K2 + B * T * DK;
  float* C4 = K3 + B * T * DK;
  float* C5 = C4 + B * T * DK;

  k_all_learning<<<dim3(B * 16), dim3(DK), 0, stream>>>(qs, ats, corr, e_w, at_w, W1, b1, AL);
  k_consts<<<dim3(B * 16), dim3(DK), 0, stream>>>(qs, its, it_w, e_w, AL,
                                                  W2, b2, W3, b3, W4, b4, W5, b5,
                                                  K2, K3, C4, C5);
  k_scan<<<dim3(B), dim3(512), 0, stream>>>(qs, qmat, h0, K2, K3, C4, C5,
                                            W2, W3, W4, W5, out);
}